// Round 5
// baseline (764.857 us; speedup 1.0000x reference)
//
#include <hip/hip_runtime.h>
#include <hip/hip_cooperative_groups.h>
#include <math.h>

namespace cg = cooperative_groups;

#define LUTN 1024
#define LUTSCALE 512.0f

// ---------------- fused cooperative pipeline ----------------
// P0 init (zero cnt/d2, M table, LUT) | P1 hist + bucket + coalesced rec |
// P2 chunk scan | P3 chunk-offset scan + apply + d2 transform | P4 id scatter |
// P5 node accumulate -> cat, swb.   Epilogue GEMM is a separate kernel.

__global__ __launch_bounds__(256, 6) void fused_kernel(
    const float* __restrict__ feat, const float* __restrict__ loc,
    const float* __restrict__ boundaries, const float* __restrict__ embed,
    const float* __restrict__ G_w,
    const int* __restrict__ src, const int* __restrict__ dst,
    const int* __restrict__ inter,
    float* __restrict__ M, int* __restrict__ lut,
    float* __restrict__ d2, int* __restrict__ cnt,
    int* __restrict__ start, int* __restrict__ cursor, int* __restrict__ part,
    int4* __restrict__ recA, int2* __restrict__ recB, int* __restrict__ order,
    float* __restrict__ cat, float* __restrict__ swb,
    int N, int E)
{
    cg::grid_group grid = cg::this_grid();
    const int tid  = threadIdx.x;
    const int gsz  = (int)gridDim.x * 256;
    const int gid0 = (int)blockIdx.x * 256 + tid;

    __shared__ float Ms[4096];      // 16 KB (P5)
    __shared__ int   lut_s[LUTN];   // 4 KB  (P1)
    __shared__ float bl[64];
    __shared__ int   po[256];       // chunk offsets (P3)
    __shared__ int   wtmp[8];

    // ---- P0: init ----
    for (int i = gid0; i < N; i += gsz) { cnt[i] = 0; d2[i] = 0.f; }
    for (int i = gid0; i < 64 * 64; i += gsz) {
        int b = i >> 6, f = i & 63;
        float acc = 0.f;
        #pragma unroll
        for (int dd = 0; dd < 32; ++dd) acc += embed[b * 32 + dd] * G_w[f * 32 + dd];
        M[i] = acc;
    }
    for (int i = gid0; i < LUTN; i += gsz) {
        float left = (float)i * (1.0f / LUTSCALE);
        int c = 0;
        for (int j = 0; j < 63; ++j) c += (boundaries[j] < left) ? 1 : 0;
        lut[i] = c;
    }
    grid.sync();

    // ---- P1: hist + bucket + coalesced records ----
    ((int4*)lut_s)[tid] = ((const int4*)lut)[tid];
    if (tid < 64) bl[tid] = (tid < 63) ? boundaries[tid] : 3.4e38f;
    __syncthreads();
    for (int e = gid0; e < E; e += gsz) {
        const int s = src[e], d = dst[e];
        const int4 ii = ((const int4*)inter)[e];
        atomicAdd(&cnt[d], 1);
        atomicAdd(&d2[s], 1.0f);
        const float sx = loc[3 * s], sy = loc[3 * s + 1], sz = loc[3 * s + 2];
        float dist[5];
        {
            float dx = loc[3 * d] - sx, dy = loc[3 * d + 1] - sy, dz = loc[3 * d + 2] - sz;
            dist[0] = sqrtf(dx * dx + dy * dy + dz * dz);
        }
        const int id4[4] = {ii.x, ii.y, ii.z, ii.w};
        #pragma unroll
        for (int j = 0; j < 4; ++j) {
            int t = id4[j];
            float dx = loc[3 * t] - sx, dy = loc[3 * t + 1] - sy, dz = loc[3 * t + 2] - sz;
            dist[1 + j] = sqrtf(dx * dx + dy * dy + dz * dz);
        }
        unsigned pack = 0;
        #pragma unroll
        for (int q = 0; q < 5; ++q) {
            float dq = dist[q];
            int cell = (int)(dq * LUTSCALE);
            cell = (cell > LUTN - 1) ? (LUTN - 1) : cell;
            int b = lut_s[cell];
            while (b < 63 && bl[b] < dq) ++b;
            while (b > 0 && bl[b - 1] >= dq) --b;
            pack |= ((unsigned)b) << (6 * q);
        }
        recA[e] = ii;                       // coalesced 16 B
        recB[e] = make_int2(s, (int)pack);  // coalesced 8 B
    }
    grid.sync();

    // ---- P2: per-256-chunk scan of cnt ----  (requires N <= 256*256)
    const int nchunks = (N + 255) >> 8;
    for (int c = blockIdx.x; c < nchunks; c += gridDim.x) {
        int i = c * 256 + tid;
        int v = (i < N) ? cnt[i] : 0;
        int lane = tid & 63, wv = tid >> 6;
        int x = v;
        #pragma unroll
        for (int off = 1; off < 64; off <<= 1) { int y = __shfl_up(x, off); if (lane >= off) x += y; }
        if (lane == 63) wtmp[wv] = x;
        __syncthreads();
        if (tid < 4) {
            int w = wtmp[tid], xx = w;
            #pragma unroll
            for (int off = 1; off < 4; off <<= 1) { int y = __shfl_up(xx, off); if (tid >= off) xx += y; }
            wtmp[tid] = xx - w;
        }
        __syncthreads();
        int incl = x + wtmp[wv];
        if (i < N) start[i] = incl - v;   // chunk-local exclusive
        if (tid == 255) part[c] = incl;
        __syncthreads();
    }
    grid.sync();

    // ---- P3: redundant per-block scan of part[] + apply + d2 transform ----
    {
        int v = (tid < nchunks) ? part[tid] : 0;
        int lane = tid & 63, wv = tid >> 6;
        int x = v;
        #pragma unroll
        for (int off = 1; off < 64; off <<= 1) { int y = __shfl_up(x, off); if (lane >= off) x += y; }
        if (lane == 63) wtmp[wv] = x;
        __syncthreads();
        if (tid < 4) {
            int w = wtmp[tid], xx = w;
            #pragma unroll
            for (int off = 1; off < 4; off <<= 1) { int y = __shfl_up(xx, off); if (tid >= off) xx += y; }
            wtmp[tid] = xx - w;
        }
        __syncthreads();
        po[tid] = x + wtmp[wv] - v;       // exclusive chunk offset
        __syncthreads();
        for (int i = gid0; i < N; i += gsz) {
            int s2 = start[i] + po[i >> 8];
            start[i] = s2;
            cursor[i] = s2;
            d2[i] = 1.0f / sqrtf(fmaxf(d2[i], 1.0f));
        }
    }
    grid.sync();

    // ---- P4: scatter edge ids (4 B) ----
    for (int e = gid0; e < E; e += gsz) {
        int p = atomicAdd(&cursor[dst[e]], 1);
        order[p] = e;
    }
    grid.sync();

    // ---- P5: wave-per-node accumulate ----
    #pragma unroll
    for (int i = 0; i < 4; ++i)
        ((float4*)Ms)[tid + 256 * i] = ((const float4*)M)[tid + 256 * i];
    __syncthreads();
    const int lane = tid & 63, wid = tid >> 6;
    const int gw = (int)blockIdx.x * 4 + wid, gstride = (int)gridDim.x * 4;
    for (int d = gw; d < N; d += gstride) {
        const int deg  = __builtin_amdgcn_readfirstlane(cnt[d]);
        const int base = __builtin_amdgcn_readfirstlane(start[d]);
        float acc0 = 0.f, acc1 = 0.f, sw = 0.f;
        #pragma unroll 4
        for (int k = 0; k < deg; ++k) {
            const int eid = order[base + k];     // wave-uniform broadcast
            const int4 ra = recA[eid];
            const int2 rb = recB[eid];
            const float w = d2[rb.x];
            const unsigned pk = (unsigned)rb.y;
            const float fs = feat[(size_t)rb.x * 64 + lane];
            const float f0 = feat[(size_t)ra.x * 64 + lane];
            const float f1 = feat[(size_t)ra.y * 64 + lane];
            const float f2 = feat[(size_t)ra.z * 64 + lane];
            const float f3 = feat[(size_t)ra.w * 64 + lane];
            const float m0 = Ms[(pk & 63u) * 64 + lane];
            const float m1 = Ms[((pk >> 6) & 63u) * 64 + lane];
            const float m2 = Ms[((pk >> 12) & 63u) * 64 + lane];
            const float m3 = Ms[((pk >> 18) & 63u) * 64 + lane];
            const float m4 = Ms[((pk >> 24) & 63u) * 64 + lane];
            acc0 = fmaf(m0 * fs, w, acc0);
            float t = m1 * f0 + m2 * f1 + m3 * f2 + m4 * f3;
            acc1 = fmaf(0.25f * t, w, acc1);
            sw += w;
        }
        cat[(size_t)d * 128 + lane]      = acc0;
        cat[(size_t)d * 128 + 64 + lane] = acc1;
        if (lane == 0) swb[d] = sw;
    }
}

// ---------------- epilogue GEMM: out = d0 * (cat @ agg_w^T + bias*sw) ----------------

__global__ __launch_bounds__(256) void epilogue_kernel(
    const float* __restrict__ cat, const float* __restrict__ agg_w,
    const float* __restrict__ agg_b, const float* __restrict__ swb,
    const int* __restrict__ cnt, float* __restrict__ out, int N) {

    const int lane = threadIdx.x & 63;
    const int wid  = threadIdx.x >> 6;

    float4 aw[32];
    const float4* awp = (const float4*)(agg_w + (size_t)lane * 128);
    #pragma unroll
    for (int i = 0; i < 32; ++i) aw[i] = awp[i];
    const float bias = agg_b[lane];

    const int gw = blockIdx.x * 4 + wid;
    const int stride = gridDim.x * 4;

    for (int d0i = gw; d0i < N; d0i += stride) {
        const int du = __builtin_amdgcn_readfirstlane(d0i);
        const float* cp = cat + (size_t)du * 128;
        float acc = bias * swb[du];
        #pragma unroll
        for (int k4 = 0; k4 < 32; ++k4) {
            float4 c = ((const float4*)cp)[k4];
            acc = fmaf(aw[k4].x, c.x, acc);
            acc = fmaf(aw[k4].y, c.y, acc);
            acc = fmaf(aw[k4].z, c.z, acc);
            acc = fmaf(aw[k4].w, c.w, acc);
        }
        const float d0v = rsqrtf(fmaxf((float)cnt[du], 1.0f));
        out[(size_t)du * 64 + lane] = d0v * acc;
    }
}

// ---------------- launch ----------------

extern "C" void kernel_launch(void* const* d_in, const int* in_sizes, int n_in,
                              void* d_out, int out_size, void* d_ws, size_t ws_size,
                              hipStream_t stream) {
    const float* feat       = (const float*)d_in[0];
    const float* loc        = (const float*)d_in[1];
    const float* boundaries = (const float*)d_in[2];
    const float* embed      = (const float*)d_in[3];
    const float* G_w        = (const float*)d_in[4];
    const float* agg_w      = (const float*)d_in[5];
    const float* agg_b      = (const float*)d_in[6];
    const int*   src        = (const int*)d_in[7];
    const int*   dst        = (const int*)d_in[8];
    const int*   inter      = (const int*)d_in[9];

    const int N = in_sizes[0] / 64;   // 50000
    const int E = in_sizes[7];        // 500000

    // ws layout (ints/floats, 16B-aligned sections)
    char* w = (char*)d_ws;
    auto take = [&](size_t bytes) { char* p = w; w += (bytes + 15) & ~(size_t)15; return p; };
    float* M      = (float*)take(4096 * 4);
    int*   lut    = (int*)  take(LUTN * 4);
    float* d2     = (float*)take((size_t)N * 4);
    int*   cnt    = (int*)  take((size_t)N * 4);
    int*   start  = (int*)  take((size_t)N * 4);
    int*   cursor = (int*)  take((size_t)N * 4);
    int*   part   = (int*)  take(256 * 4);
    int4*  recA   = (int4*) take((size_t)E * 16);
    int2*  recB   = (int2*) take((size_t)E * 8);
    int*   order  = (int*)  take((size_t)E * 4);
    float* cat    = (float*)take((size_t)N * 128 * 4);
    float* swb    = (float*)take((size_t)N * 4);
    float* out    = (float*)d_out;

    // co-resident grid size (host query runs at capture time only)
    int blocksPerCU = 0;
    hipOccupancyMaxActiveBlocksPerMultiprocessor(&blocksPerCU, fused_kernel, 256, 0);
    if (blocksPerCU < 1) blocksPerCU = 1;
    int grid = blocksPerCU * 256;          // 256 CUs on MI355X
    if (grid > 4096) grid = 4096;

    int Nv = N, Ev = E;
    void* args[] = {
        (void*)&feat, (void*)&loc, (void*)&boundaries, (void*)&embed, (void*)&G_w,
        (void*)&src, (void*)&dst, (void*)&inter,
        (void*)&M, (void*)&lut, (void*)&d2, (void*)&cnt,
        (void*)&start, (void*)&cursor, (void*)&part,
        (void*)&recA, (void*)&recB, (void*)&order,
        (void*)&cat, (void*)&swb, (void*)&Nv, (void*)&Ev
    };
    hipLaunchCooperativeKernel((const void*)fused_kernel, dim3(grid), dim3(256),
                               args, 0, stream);

    epilogue_kernel<<<768, 256, 0, stream>>>(cat, agg_w, agg_b, swb, cnt, out, N);
}

// Round 6
// 259.337 us; speedup vs baseline: 2.9493x; 2.9493x over previous
//
#include <hip/hip_runtime.h>
#include <math.h>

#define LUTN 1024
#define LUTSCALE 512.0f

// ---------------- K1: setup (zero cnt/d2, M table, LUT) ----------------

__global__ __launch_bounds__(256) void setup_kernel(
    const float* __restrict__ embed, const float* __restrict__ G_w,
    const float* __restrict__ boundaries,
    float* __restrict__ M, int* __restrict__ lut,
    int* __restrict__ d2i, int* __restrict__ cnt, int N) {

    const int gid = blockIdx.x * 256 + threadIdx.x;
    const int gsz = gridDim.x * 256;
    for (int i = gid; i < N; i += gsz) { cnt[i] = 0; d2i[i] = 0; }
    for (int i = gid; i < 4096; i += gsz) {
        int b = i >> 6, f = i & 63;
        float acc = 0.f;
        #pragma unroll
        for (int dd = 0; dd < 32; ++dd) acc += embed[b * 32 + dd] * G_w[f * 32 + dd];
        M[i] = acc;
    }
    for (int i = gid; i < LUTN; i += gsz) {
        float left = (float)i * (1.0f / LUTSCALE);
        int c = 0;
        for (int j = 0; j < 63; ++j) c += (boundaries[j] < left) ? 1 : 0;
        lut[i] = c;
    }
}

// ---------------- K2: edge pass — bucket + rank atomic + d2 atomic ----------------
// recEA[e] = {i0,i1,i2,i3};  recEB[e] = {s, pack, rank, 0}   (coalesced writes)

__global__ __launch_bounds__(256) void edge_kernel(
    const float* __restrict__ loc, const float* __restrict__ boundaries,
    const int* __restrict__ lut,
    const int* __restrict__ src, const int* __restrict__ dst,
    const int* __restrict__ inter,
    int* __restrict__ cnt, int* __restrict__ d2i,
    int4* __restrict__ recEA, int4* __restrict__ recEB, int E) {

    __shared__ int lut_s[LUTN];
    __shared__ float bl[64];
    ((int4*)lut_s)[threadIdx.x] = ((const int4*)lut)[threadIdx.x];
    if (threadIdx.x < 64)
        bl[threadIdx.x] = (threadIdx.x < 63) ? boundaries[threadIdx.x] : 3.4e38f;
    __syncthreads();

    const int e = blockIdx.x * 256 + threadIdx.x;
    if (e >= E) return;

    const int s = src[e], d = dst[e];
    const int4 ii = ((const int4*)inter)[e];

    const float sx = loc[3 * s], sy = loc[3 * s + 1], sz = loc[3 * s + 2];
    float dist[5];
    {
        float dx = loc[3 * d] - sx, dy = loc[3 * d + 1] - sy, dz = loc[3 * d + 2] - sz;
        dist[0] = sqrtf(dx * dx + dy * dy + dz * dz);
    }
    const int id4[4] = {ii.x, ii.y, ii.z, ii.w};
    #pragma unroll
    for (int j = 0; j < 4; ++j) {
        int t = id4[j];
        float dx = loc[3 * t] - sx, dy = loc[3 * t + 1] - sy, dz = loc[3 * t + 2] - sz;
        dist[1 + j] = sqrtf(dx * dx + dy * dy + dz * dz);
    }
    unsigned pack = 0;
    #pragma unroll
    for (int q = 0; q < 5; ++q) {
        float dq = dist[q];
        int cell = (int)(dq * LUTSCALE);
        cell = (cell > LUTN - 1) ? (LUTN - 1) : cell;
        int b = lut_s[cell];
        while (b < 63 && bl[b] < dq) ++b;
        while (b > 0 && bl[b - 1] >= dq) --b;
        pack |= ((unsigned)b) << (6 * q);
    }

    const int r = atomicAdd(&cnt[d], 1);   // rank within dst segment + final deg
    atomicAdd(&d2i[s], 1);                 // out-degree histogram

    recEA[e] = ii;
    recEB[e] = make_int4(s, (int)pack, r, 0);
}

// ---------------- K3: chunk scan of cnt + d2 transform ----------------

__global__ __launch_bounds__(1024) void scan_block_kernel(
    const int* __restrict__ cnt, int* __restrict__ startv,
    int* __restrict__ part, int* __restrict__ d2buf, int N) {

    __shared__ int wsum[16];
    const int t = threadIdx.x, lane = t & 63, wv = t >> 6;
    const int i = blockIdx.x * 1024 + t;

    // d2 transform (in place: int count -> float rsqrt), independent of scan
    if (i < N) {
        float v = (float)d2buf[i];
        ((float*)d2buf)[i] = rsqrtf(fmaxf(v, 1.0f));
    }

    int v = (i < N) ? cnt[i] : 0;
    int x = v;
    #pragma unroll
    for (int off = 1; off < 64; off <<= 1) { int y = __shfl_up(x, off); if (lane >= off) x += y; }
    if (lane == 63) wsum[wv] = x;
    __syncthreads();
    if (t < 16) {
        int w = wsum[t], xx = w;
        #pragma unroll
        for (int off = 1; off < 16; off <<= 1) { int y = __shfl_up(xx, off); if (t >= off) xx += y; }
        wsum[t] = xx - w;
    }
    __syncthreads();
    int incl = x + wsum[wv];
    if (i < N) startv[i] = incl - v;              // block-local exclusive
    if (t == 1023) part[blockIdx.x] = incl;
}

__global__ __launch_bounds__(1024) void scan_fix_kernel(
    int* __restrict__ startv, const int* __restrict__ part, int N, int nb) {

    __shared__ int po;
    if (threadIdx.x == 0) {
        int s = 0;
        for (int j = 0; j < (int)blockIdx.x; ++j) s += part[j];   // nb <= 64, cheap
        po = s;
    }
    __syncthreads();
    int i = blockIdx.x * 1024 + threadIdx.x;
    if (i < N) startv[i] += po;
}

// ---------------- K5: atomic-free scatter of fat records ----------------
// rec[pos] = {s,i0,i1,i2} {i3,pack,w,0}  with pos = start[dst] + rank

__global__ __launch_bounds__(256) void scatter_kernel(
    const int4* __restrict__ recEA, const int4* __restrict__ recEB,
    const int* __restrict__ dst, const int* __restrict__ startv,
    const float* __restrict__ d2f, int* __restrict__ rec, int E) {

    const int e = blockIdx.x * 256 + threadIdx.x;
    if (e >= E) return;
    const int4 a = recEA[e];
    const int4 b = recEB[e];
    const int d = dst[e];
    const int pos = startv[d] + b.z;
    const float w = d2f[b.x];
    int* r = rec + (size_t)pos * 8;
    *(int4*)(r)     = make_int4(b.x, a.x, a.y, a.z);
    *(int4*)(r + 4) = make_int4(a.w, b.y, __float_as_int(w), 0);
}

// ---------------- K6: wave-per-node gather + accumulate (round-4 proven) ----------------

__global__ __launch_bounds__(256) void node_kernel(
    const float* __restrict__ feat, const float* __restrict__ M,
    const int* __restrict__ cnt, const int* __restrict__ startv,
    const int* __restrict__ rec, float* __restrict__ cat,
    float* __restrict__ swb, int N) {

    __shared__ float Ms[4096];
    #pragma unroll
    for (int i = 0; i < 4; ++i)
        ((float4*)Ms)[threadIdx.x + 256 * i] = ((const float4*)M)[threadIdx.x + 256 * i];
    __syncthreads();

    const int lane = threadIdx.x & 63;
    const int wid  = threadIdx.x >> 6;
    const int d    = blockIdx.x * 4 + wid;
    if (d >= N) return;

    const int deg  = __builtin_amdgcn_readfirstlane(cnt[d]);
    const int base = __builtin_amdgcn_readfirstlane(startv[d]);
    const int* rp  = rec + (size_t)base * 8;

    float acc0 = 0.f, acc1 = 0.f, sw = 0.f;

    #pragma unroll 4
    for (int k = 0; k < deg; ++k) {
        const int s  = rp[k * 8 + 0];
        const int i0 = rp[k * 8 + 1];
        const int i1 = rp[k * 8 + 2];
        const int i2 = rp[k * 8 + 3];
        const int i3 = rp[k * 8 + 4];
        const unsigned pk = (unsigned)rp[k * 8 + 5];
        const float w = __int_as_float(rp[k * 8 + 6]);

        const float fs = feat[(size_t)s  * 64 + lane];
        const float f0 = feat[(size_t)i0 * 64 + lane];
        const float f1 = feat[(size_t)i1 * 64 + lane];
        const float f2 = feat[(size_t)i2 * 64 + lane];
        const float f3 = feat[(size_t)i3 * 64 + lane];
        const float m0 = Ms[(pk & 63u) * 64 + lane];
        const float m1 = Ms[((pk >> 6) & 63u) * 64 + lane];
        const float m2 = Ms[((pk >> 12) & 63u) * 64 + lane];
        const float m3 = Ms[((pk >> 18) & 63u) * 64 + lane];
        const float m4 = Ms[((pk >> 24) & 63u) * 64 + lane];

        acc0 = fmaf(m0 * fs, w, acc0);
        float t = m1 * f0 + m2 * f1 + m3 * f2 + m4 * f3;
        acc1 = fmaf(0.25f * t, w, acc1);
        sw += w;
    }

    cat[(size_t)d * 128 + lane]      = acc0;
    cat[(size_t)d * 128 + 64 + lane] = acc1;
    if (lane == 0) swb[d] = sw;
}

// ---------------- K7: epilogue GEMM  out = d0 * (cat @ agg_w^T + bias*sw) ----------------

__global__ __launch_bounds__(256) void epilogue_kernel(
    const float* __restrict__ cat, const float* __restrict__ agg_w,
    const float* __restrict__ agg_b, const float* __restrict__ swb,
    const int* __restrict__ cnt, float* __restrict__ out, int N) {

    const int lane = threadIdx.x & 63;
    const int wid  = threadIdx.x >> 6;

    float4 aw[32];
    const float4* awp = (const float4*)(agg_w + (size_t)lane * 128);
    #pragma unroll
    for (int i = 0; i < 32; ++i) aw[i] = awp[i];
    const float bias = agg_b[lane];

    const int gw = blockIdx.x * 4 + wid;
    const int stride = gridDim.x * 4;

    for (int d0i = gw; d0i < N; d0i += stride) {
        const int du = __builtin_amdgcn_readfirstlane(d0i);
        const float* cp = cat + (size_t)du * 128;
        float a0 = bias * swb[du], a1 = 0.f, a2 = 0.f, a3 = 0.f;
        #pragma unroll
        for (int k4 = 0; k4 < 32; k4 += 4) {     // 4 parallel chains
            float4 c0 = ((const float4*)cp)[k4];
            float4 c1 = ((const float4*)cp)[k4 + 1];
            float4 c2 = ((const float4*)cp)[k4 + 2];
            float4 c3 = ((const float4*)cp)[k4 + 3];
            a0 = fmaf(aw[k4].x, c0.x, a0); a0 = fmaf(aw[k4].y, c0.y, a0);
            a0 = fmaf(aw[k4].z, c0.z, a0); a0 = fmaf(aw[k4].w, c0.w, a0);
            a1 = fmaf(aw[k4+1].x, c1.x, a1); a1 = fmaf(aw[k4+1].y, c1.y, a1);
            a1 = fmaf(aw[k4+1].z, c1.z, a1); a1 = fmaf(aw[k4+1].w, c1.w, a1);
            a2 = fmaf(aw[k4+2].x, c2.x, a2); a2 = fmaf(aw[k4+2].y, c2.y, a2);
            a2 = fmaf(aw[k4+2].z, c2.z, a2); a2 = fmaf(aw[k4+2].w, c2.w, a2);
            a3 = fmaf(aw[k4+3].x, c3.x, a3); a3 = fmaf(aw[k4+3].y, c3.y, a3);
            a3 = fmaf(aw[k4+3].z, c3.z, a3); a3 = fmaf(aw[k4+3].w, c3.w, a3);
        }
        const float d0v = rsqrtf(fmaxf((float)cnt[du], 1.0f));
        out[(size_t)du * 64 + lane] = d0v * ((a0 + a1) + (a2 + a3));
    }
}

// ---------------- launch ----------------

extern "C" void kernel_launch(void* const* d_in, const int* in_sizes, int n_in,
                              void* d_out, int out_size, void* d_ws, size_t ws_size,
                              hipStream_t stream) {
    const float* feat       = (const float*)d_in[0];
    const float* loc        = (const float*)d_in[1];
    const float* boundaries = (const float*)d_in[2];
    const float* embed      = (const float*)d_in[3];
    const float* G_w        = (const float*)d_in[4];
    const float* agg_w      = (const float*)d_in[5];
    const float* agg_b      = (const float*)d_in[6];
    const int*   src        = (const int*)d_in[7];
    const int*   dst        = (const int*)d_in[8];
    const int*   inter      = (const int*)d_in[9];

    const int N = in_sizes[0] / 64;   // 50000
    const int E = in_sizes[7];        // 500000

    char* w = (char*)d_ws;
    auto take = [&](size_t bytes) { char* p = w; w += (bytes + 15) & ~(size_t)15; return p; };
    float* M      = (float*)take(4096 * 4);
    int*   lut    = (int*)  take(LUTN * 4);
    int*   d2buf  = (int*)  take((size_t)N * 4);   // int hist -> float rsqrt in place
    int*   cnt    = (int*)  take((size_t)N * 4);
    int*   startv = (int*)  take((size_t)N * 4);
    int*   part   = (int*)  take(256 * 4);
    int4*  recEA  = (int4*) take((size_t)E * 16);
    int4*  recEB  = (int4*) take((size_t)E * 16);
    int*   rec    = (int*)  take((size_t)E * 32);
    float* cat    = (float*)take((size_t)N * 128 * 4);
    float* swb    = (float*)take((size_t)N * 4);
    float* out    = (float*)d_out;

    const int nb = (N + 1023) / 1024;   // 49
    const int eb = (E + 255) / 256;     // 1954

    setup_kernel<<<256, 256, 0, stream>>>(embed, G_w, boundaries, M, lut, d2buf, cnt, N);
    edge_kernel<<<eb, 256, 0, stream>>>(loc, boundaries, lut, src, dst, inter,
                                        cnt, d2buf, recEA, recEB, E);
    scan_block_kernel<<<nb, 1024, 0, stream>>>(cnt, startv, part, d2buf, N);
    scan_fix_kernel<<<nb, 1024, 0, stream>>>(startv, part, N, nb);
    scatter_kernel<<<eb, 256, 0, stream>>>(recEA, recEB, dst, startv,
                                           (const float*)d2buf, rec, E);
    node_kernel<<<(N + 3) / 4, 256, 0, stream>>>(feat, M, cnt, startv, rec, cat, swb, N);
    epilogue_kernel<<<768, 256, 0, stream>>>(cat, agg_w, agg_b, swb, cnt, out, N);
}

// Round 7
// 241.949 us; speedup vs baseline: 3.1612x; 1.0719x over previous
//
#include <hip/hip_runtime.h>
#include <math.h>

#define LUTN 1024
#define LUTSCALE 512.0f

// ---------------- K1: setup (zero cnt/d2, M table, LUT, feat->bf16, loc->float4) ----------------

__global__ __launch_bounds__(256) void setup_kernel(
    const float* __restrict__ embed, const float* __restrict__ G_w,
    const float* __restrict__ boundaries, const float* __restrict__ feat,
    const float* __restrict__ loc,
    float* __restrict__ M, int* __restrict__ lut,
    int* __restrict__ d2i, int* __restrict__ cnt,
    unsigned short* __restrict__ featH, float4* __restrict__ loc4, int N) {

    const int gid = blockIdx.x * 256 + threadIdx.x;
    const int gsz = gridDim.x * 256;
    for (int i = gid; i < N; i += gsz) { cnt[i] = 0; d2i[i] = 0; }
    for (int i = gid; i < 4096; i += gsz) {
        int b = i >> 6, f = i & 63;
        float acc = 0.f;
        #pragma unroll
        for (int dd = 0; dd < 32; ++dd) acc += embed[b * 32 + dd] * G_w[f * 32 + dd];
        M[i] = acc;
    }
    for (int i = gid; i < LUTN; i += gsz) {
        float left = (float)i * (1.0f / LUTSCALE);
        int c = 0;
        for (int j = 0; j < 63; ++j) c += (boundaries[j] < left) ? 1 : 0;
        lut[i] = c;
    }
    // feat -> bf16 (RNE), vectorized: float4 in, ushort4 out
    const int nq = N * 16;   // N*64/4
    for (int i = gid; i < nq; i += gsz) {
        float4 v = ((const float4*)feat)[i];
        unsigned ux = __float_as_uint(v.x), uy = __float_as_uint(v.y);
        unsigned uz = __float_as_uint(v.z), uw = __float_as_uint(v.w);
        ushort4 h;
        h.x = (unsigned short)((ux + 0x7FFFu + ((ux >> 16) & 1u)) >> 16);
        h.y = (unsigned short)((uy + 0x7FFFu + ((uy >> 16) & 1u)) >> 16);
        h.z = (unsigned short)((uz + 0x7FFFu + ((uz >> 16) & 1u)) >> 16);
        h.w = (unsigned short)((uw + 0x7FFFu + ((uw >> 16) & 1u)) >> 16);
        ((ushort4*)featH)[i] = h;
    }
    for (int i = gid; i < N; i += gsz)
        loc4[i] = make_float4(loc[3 * i], loc[3 * i + 1], loc[3 * i + 2], 0.f);
}

// ---------------- K2: edge pass — bucket + rank atomic + d2 atomic ----------------
// recEA[e] = {i0,i1,i2,i3};  recEB[e] = {s | rank<<16, pack}

__global__ __launch_bounds__(256) void edge_kernel(
    const float4* __restrict__ loc4, const float* __restrict__ boundaries,
    const int* __restrict__ lut,
    const int* __restrict__ src, const int* __restrict__ dst,
    const int* __restrict__ inter,
    int* __restrict__ cnt, int* __restrict__ d2i,
    int4* __restrict__ recEA, int2* __restrict__ recEB, int E) {

    __shared__ int lut_s[LUTN];
    __shared__ float bl[64];
    ((int4*)lut_s)[threadIdx.x] = ((const int4*)lut)[threadIdx.x];
    if (threadIdx.x < 64)
        bl[threadIdx.x] = (threadIdx.x < 63) ? boundaries[threadIdx.x] : 3.4e38f;
    __syncthreads();

    const int e = blockIdx.x * 256 + threadIdx.x;
    if (e >= E) return;

    const int s = src[e], d = dst[e];
    const int4 ii = ((const int4*)inter)[e];

    const float4 ps = loc4[s];
    float dist[5];
    {
        float4 pd = loc4[d];
        float dx = pd.x - ps.x, dy = pd.y - ps.y, dz = pd.z - ps.z;
        dist[0] = sqrtf(dx * dx + dy * dy + dz * dz);
    }
    const int id4[4] = {ii.x, ii.y, ii.z, ii.w};
    #pragma unroll
    for (int j = 0; j < 4; ++j) {
        float4 pt = loc4[id4[j]];
        float dx = pt.x - ps.x, dy = pt.y - ps.y, dz = pt.z - ps.z;
        dist[1 + j] = sqrtf(dx * dx + dy * dy + dz * dz);
    }
    unsigned pack = 0;
    #pragma unroll
    for (int q = 0; q < 5; ++q) {
        float dq = dist[q];
        int cell = (int)(dq * LUTSCALE);
        cell = (cell > LUTN - 1) ? (LUTN - 1) : cell;
        int b = lut_s[cell];
        while (b < 63 && bl[b] < dq) ++b;
        while (b > 0 && bl[b - 1] >= dq) --b;
        pack |= ((unsigned)b) << (6 * q);
    }

    const int r = atomicAdd(&cnt[d], 1);   // rank within dst segment (max deg << 65536)
    atomicAdd(&d2i[s], 1);                 // out-degree histogram

    recEA[e] = ii;
    recEB[e] = make_int2(s | (r << 16), (int)pack);
}

// ---------------- K3: chunk scan of cnt + d2 transform ----------------

__global__ __launch_bounds__(1024) void scan_block_kernel(
    const int* __restrict__ cnt, int* __restrict__ startv,
    int* __restrict__ part, int* __restrict__ d2buf, int N) {

    __shared__ int wsum[16];
    const int t = threadIdx.x, lane = t & 63, wv = t >> 6;
    const int i = blockIdx.x * 1024 + t;

    if (i < N) {
        float v = (float)d2buf[i];
        ((float*)d2buf)[i] = rsqrtf(fmaxf(v, 1.0f));
    }

    int v = (i < N) ? cnt[i] : 0;
    int x = v;
    #pragma unroll
    for (int off = 1; off < 64; off <<= 1) { int y = __shfl_up(x, off); if (lane >= off) x += y; }
    if (lane == 63) wsum[wv] = x;
    __syncthreads();
    if (t < 16) {
        int w = wsum[t], xx = w;
        #pragma unroll
        for (int off = 1; off < 16; off <<= 1) { int y = __shfl_up(xx, off); if (t >= off) xx += y; }
        wsum[t] = xx - w;
    }
    __syncthreads();
    int incl = x + wsum[wv];
    if (i < N) startv[i] = incl - v;
    if (t == 1023) part[blockIdx.x] = incl;
}

__global__ __launch_bounds__(1024) void scan_fix_kernel(
    int* __restrict__ startv, const int* __restrict__ part, int N, int nb) {

    __shared__ int po;
    if (threadIdx.x == 0) {
        int s = 0;
        for (int j = 0; j < (int)blockIdx.x; ++j) s += part[j];
        po = s;
    }
    __syncthreads();
    int i = blockIdx.x * 1024 + threadIdx.x;
    if (i < N) startv[i] += po;
}

// ---------------- K5: atomic-free scatter of fat records ----------------
// rec[pos] = {s,i0,i1,i2} {i3,pack,w,0}  with pos = start[dst] + rank

__global__ __launch_bounds__(256) void scatter_kernel(
    const int4* __restrict__ recEA, const int2* __restrict__ recEB,
    const int* __restrict__ dst, const int* __restrict__ startv,
    const float* __restrict__ d2f, int* __restrict__ rec, int E) {

    const int e = blockIdx.x * 256 + threadIdx.x;
    if (e >= E) return;
    const int4 a = recEA[e];
    const int2 b = recEB[e];
    const int s = b.x & 0xFFFF;
    const int r = ((unsigned)b.x) >> 16;
    const int d = dst[e];
    const int pos = startv[d] + r;
    const float w = d2f[s];
    int* rp = rec + (size_t)pos * 8;
    *(int4*)(rp)     = make_int4(s, a.x, a.y, a.z);
    *(int4*)(rp + 4) = make_int4(a.w, b.y, __float_as_int(w), 0);
}

// ---------------- K6: wave-per-node gather (bf16 feat) + accumulate ----------------

__global__ __launch_bounds__(256) void node_kernel(
    const unsigned short* __restrict__ featH, const float* __restrict__ M,
    const int* __restrict__ cnt, const int* __restrict__ startv,
    const int* __restrict__ rec, float* __restrict__ cat,
    float* __restrict__ swb, int N) {

    __shared__ float Ms[4096];
    #pragma unroll
    for (int i = 0; i < 4; ++i)
        ((float4*)Ms)[threadIdx.x + 256 * i] = ((const float4*)M)[threadIdx.x + 256 * i];
    __syncthreads();

    const int lane = threadIdx.x & 63;
    const int wid  = threadIdx.x >> 6;
    const int d    = blockIdx.x * 4 + wid;
    if (d >= N) return;

    const int deg  = __builtin_amdgcn_readfirstlane(cnt[d]);
    const int base = __builtin_amdgcn_readfirstlane(startv[d]);
    const int* rp  = rec + (size_t)base * 8;

    float acc0 = 0.f, acc1 = 0.f, sw = 0.f;

    #pragma unroll 4
    for (int k = 0; k < deg; ++k) {
        const int s  = rp[k * 8 + 0];
        const int i0 = rp[k * 8 + 1];
        const int i1 = rp[k * 8 + 2];
        const int i2 = rp[k * 8 + 3];
        const int i3 = rp[k * 8 + 4];
        const unsigned pk = (unsigned)rp[k * 8 + 5];
        const float w = __int_as_float(rp[k * 8 + 6]);

        const float fs = __uint_as_float(((unsigned)featH[(size_t)s  * 64 + lane]) << 16);
        const float f0 = __uint_as_float(((unsigned)featH[(size_t)i0 * 64 + lane]) << 16);
        const float f1 = __uint_as_float(((unsigned)featH[(size_t)i1 * 64 + lane]) << 16);
        const float f2 = __uint_as_float(((unsigned)featH[(size_t)i2 * 64 + lane]) << 16);
        const float f3 = __uint_as_float(((unsigned)featH[(size_t)i3 * 64 + lane]) << 16);
        const float m0 = Ms[(pk & 63u) * 64 + lane];
        const float m1 = Ms[((pk >> 6) & 63u) * 64 + lane];
        const float m2 = Ms[((pk >> 12) & 63u) * 64 + lane];
        const float m3 = Ms[((pk >> 18) & 63u) * 64 + lane];
        const float m4 = Ms[((pk >> 24) & 63u) * 64 + lane];

        acc0 = fmaf(m0 * fs, w, acc0);
        float t = m1 * f0 + m2 * f1 + m3 * f2 + m4 * f3;
        acc1 = fmaf(0.25f * t, w, acc1);
        sw += w;
    }

    cat[(size_t)d * 128 + lane]      = acc0;
    cat[(size_t)d * 128 + 64 + lane] = acc1;
    if (lane == 0) swb[d] = sw;
}

// ---------------- K7: epilogue GEMM  out = d0 * (cat @ agg_w^T + bias*sw) ----------------

__global__ __launch_bounds__(256) void epilogue_kernel(
    const float* __restrict__ cat, const float* __restrict__ agg_w,
    const float* __restrict__ agg_b, const float* __restrict__ swb,
    const int* __restrict__ cnt, float* __restrict__ out, int N) {

    const int lane = threadIdx.x & 63;
    const int wid  = threadIdx.x >> 6;

    float4 aw[32];
    const float4* awp = (const float4*)(agg_w + (size_t)lane * 128);
    #pragma unroll
    for (int i = 0; i < 32; ++i) aw[i] = awp[i];
    const float bias = agg_b[lane];

    const int gw = blockIdx.x * 4 + wid;
    const int stride = gridDim.x * 4;

    for (int d0i = gw; d0i < N; d0i += stride) {
        const int du = __builtin_amdgcn_readfirstlane(d0i);
        const float* cp = cat + (size_t)du * 128;
        float a0 = bias * swb[du], a1 = 0.f, a2 = 0.f, a3 = 0.f;
        #pragma unroll
        for (int k4 = 0; k4 < 32; k4 += 4) {
            float4 c0 = ((const float4*)cp)[k4];
            float4 c1 = ((const float4*)cp)[k4 + 1];
            float4 c2 = ((const float4*)cp)[k4 + 2];
            float4 c3 = ((const float4*)cp)[k4 + 3];
            a0 = fmaf(aw[k4].x, c0.x, a0); a0 = fmaf(aw[k4].y, c0.y, a0);
            a0 = fmaf(aw[k4].z, c0.z, a0); a0 = fmaf(aw[k4].w, c0.w, a0);
            a1 = fmaf(aw[k4+1].x, c1.x, a1); a1 = fmaf(aw[k4+1].y, c1.y, a1);
            a1 = fmaf(aw[k4+1].z, c1.z, a1); a1 = fmaf(aw[k4+1].w, c1.w, a1);
            a2 = fmaf(aw[k4+2].x, c2.x, a2); a2 = fmaf(aw[k4+2].y, c2.y, a2);
            a2 = fmaf(aw[k4+2].z, c2.z, a2); a2 = fmaf(aw[k4+2].w, c2.w, a2);
            a3 = fmaf(aw[k4+3].x, c3.x, a3); a3 = fmaf(aw[k4+3].y, c3.y, a3);
            a3 = fmaf(aw[k4+3].z, c3.z, a3); a3 = fmaf(aw[k4+3].w, c3.w, a3);
        }
        const float d0v = rsqrtf(fmaxf((float)cnt[du], 1.0f));
        out[(size_t)du * 64 + lane] = d0v * ((a0 + a1) + (a2 + a3));
    }
}

// ---------------- launch ----------------

extern "C" void kernel_launch(void* const* d_in, const int* in_sizes, int n_in,
                              void* d_out, int out_size, void* d_ws, size_t ws_size,
                              hipStream_t stream) {
    const float* feat       = (const float*)d_in[0];
    const float* loc        = (const float*)d_in[1];
    const float* boundaries = (const float*)d_in[2];
    const float* embed      = (const float*)d_in[3];
    const float* G_w        = (const float*)d_in[4];
    const float* agg_w      = (const float*)d_in[5];
    const float* agg_b      = (const float*)d_in[6];
    const int*   src        = (const int*)d_in[7];
    const int*   dst        = (const int*)d_in[8];
    const int*   inter      = (const int*)d_in[9];

    const int N = in_sizes[0] / 64;   // 50000
    const int E = in_sizes[7];        // 500000

    char* w = (char*)d_ws;
    auto take = [&](size_t bytes) { char* p = w; w += (bytes + 15) & ~(size_t)15; return p; };
    float*          M      = (float*)take(4096 * 4);
    int*            lut    = (int*)  take(LUTN * 4);
    int*            d2buf  = (int*)  take((size_t)N * 4);
    int*            cnt    = (int*)  take((size_t)N * 4);
    int*            startv = (int*)  take((size_t)N * 4);
    int*            part   = (int*)  take(256 * 4);
    int4*           recEA  = (int4*) take((size_t)E * 16);
    int2*           recEB  = (int2*) take((size_t)E * 8);
    int*            rec    = (int*)  take((size_t)E * 32);
    float*          cat    = (float*)take((size_t)N * 128 * 4);
    float*          swb    = (float*)take((size_t)N * 4);
    unsigned short* featH  = (unsigned short*)take((size_t)N * 64 * 2);
    float4*         loc4   = (float4*)take((size_t)N * 16);
    float*          out    = (float*)d_out;

    const int nb = (N + 1023) / 1024;   // 49
    const int eb = (E + 255) / 256;     // 1954

    setup_kernel<<<1024, 256, 0, stream>>>(embed, G_w, boundaries, feat, loc,
                                           M, lut, d2buf, cnt, featH, loc4, N);
    edge_kernel<<<eb, 256, 0, stream>>>(loc4, boundaries, lut, src, dst, inter,
                                        cnt, d2buf, recEA, recEB, E);
    scan_block_kernel<<<nb, 1024, 0, stream>>>(cnt, startv, part, d2buf, N);
    scan_fix_kernel<<<nb, 1024, 0, stream>>>(startv, part, N, nb);
    scatter_kernel<<<eb, 256, 0, stream>>>(recEA, recEB, dst, startv,
                                           (const float*)d2buf, rec, E);
    node_kernel<<<(N + 3) / 4, 256, 0, stream>>>(featH, M, cnt, startv, rec, cat, swb, N);
    epilogue_kernel<<<768, 256, 0, stream>>>(cat, agg_w, agg_b, swb, cnt, out, N);
}